// Round 1
// baseline (735.006 us; speedup 1.0000x reference)
//
#include <hip/hip_runtime.h>

// Problem constants (fixed by reference)
#define N_B   8
#define C_CH  512
#define CT_T  256
#define L_T   64
#define HEADS 8
#define D_H   64
#define HW_PX 16384   // 128*128

// ---------------------------------------------------------------------------
// Kernel A: 1x1-conv projections  v = Wv@token + bv, k = (Wk@token + bk) * (log2e/8)
// Layouts: vw[n][c][l], kw[n][c][l]  (natural (N,C,L)); scale folded into k so
// the attention kernel can use exp2 directly.
// ---------------------------------------------------------------------------
__global__ __launch_bounds__(256) void proj_kernel(
    const float* __restrict__ token,
    const float* __restrict__ Wv, const float* __restrict__ bv,
    const float* __restrict__ Wk, const float* __restrict__ bk,
    float* __restrict__ vw, float* __restrict__ kw)
{
    int t = blockIdx.x * 256 + threadIdx.x;      // 8*512*64 = 262144 threads
    int l = t & (L_T - 1);
    int c = (t >> 6) & (C_CH - 1);               // wave-uniform
    int n = t >> 15;                             // wave-uniform

    const float* tok = token + (size_t)n * CT_T * L_T + l;
    const float* wv  = Wv + (size_t)c * CT_T;    // uniform rows -> scalar loads
    const float* wk  = Wk + (size_t)c * CT_T;

    float av = 0.f, ak = 0.f;
#pragma unroll 8
    for (int ct = 0; ct < CT_T; ++ct) {
        float tv = tok[ct * L_T];                // coalesced across lanes (l)
        av = fmaf(wv[ct], tv, av);
        ak = fmaf(wk[ct], tv, ak);
    }
    av += bv[c];
    ak += bk[c];
    const float kscale = 0.125f * 1.44269504088896340736f; // (1/sqrt(64)) * log2(e)
    vw[t] = av;
    kw[t] = ak * kscale;
}

// ---------------------------------------------------------------------------
// Kernel B: attention + residual. One thread per pixel-head.
//  - K,V for this (n,h) staged in LDS (16KB each); all reads are wave-uniform
//    -> broadcast, no bank conflicts.
//  - s[64]/p[64] live in VGPRs (inner l-loops fully unrolled, dd-loops rolled
//    with unroll-4 so code stays small and loads pipeline).
//  - feature read coalesced (lane = pixel); residual re-read hits LLC.
// ---------------------------------------------------------------------------
__global__ __launch_bounds__(256, 3) void attn_kernel(
    const float* __restrict__ feature,
    const float* __restrict__ vw, const float* __restrict__ kw,
    float* __restrict__ out)
{
    __shared__ float k_lds[D_H * L_T];   // k_lds[dd*64 + l]
    __shared__ float v_lds[D_H * L_T];

    int b    = blockIdx.x;               // 4096 = 8n * 8h * 64 tiles
    int tile = b & 63;
    int h    = (b >> 6) & 7;
    int n    = b >> 9;
    int px   = tile * 256 + threadIdx.x;

    const float* kb = kw + ((size_t)n * C_CH + h * D_H) * L_T;
    const float* vb = vw + ((size_t)n * C_CH + h * D_H) * L_T;
    for (int i = threadIdx.x; i < D_H * L_T; i += 256) {
        k_lds[i] = kb[i];
        v_lds[i] = vb[i];
    }
    __syncthreads();

    const float* fbase = feature + ((size_t)n * C_CH + (size_t)h * D_H) * HW_PX + px;
    float*       obase = out     + ((size_t)n * C_CH + (size_t)h * D_H) * HW_PX + px;

    float s[L_T];
#pragma unroll
    for (int l = 0; l < L_T; ++l) s[l] = 0.f;

    // --- QK^T (scale already folded into k) ---
#pragma unroll 4
    for (int dd = 0; dd < D_H; ++dd) {
        float q = fbase[(size_t)dd * HW_PX];     // coalesced across lanes
        const float* krow = &k_lds[dd * L_T];
#pragma unroll
        for (int l = 0; l < L_T; ++l) s[l] = fmaf(q, krow[l], s[l]);
    }

    // --- softmax over l (base-2 domain) ---
    float m = s[0];
#pragma unroll
    for (int l = 1; l < L_T; ++l) m = fmaxf(m, s[l]);
    float sum = 0.f;
#pragma unroll
    for (int l = 0; l < L_T; ++l) {
        s[l] = __builtin_amdgcn_exp2f(s[l] - m);
        sum += s[l];
    }
    float rinv = 1.0f / sum;
#pragma unroll
    for (int l = 0; l < L_T; ++l) s[l] *= rinv;

    // --- PV + residual add + store ---
#pragma unroll 4
    for (int dd = 0; dd < D_H; ++dd) {
        const float* vrow = &v_lds[dd * L_T];
        float acc = 0.f;
#pragma unroll
        for (int l = 0; l < L_T; ++l) acc = fmaf(s[l], vrow[l], acc);
        obase[(size_t)dd * HW_PX] = fbase[(size_t)dd * HW_PX] + acc;  // residual re-read: LLC hit
    }
}

// ---------------------------------------------------------------------------
extern "C" void kernel_launch(void* const* d_in, const int* in_sizes, int n_in,
                              void* d_out, int out_size, void* d_ws, size_t ws_size,
                              hipStream_t stream)
{
    const float* feature = (const float*)d_in[0];
    const float* token   = (const float*)d_in[1];
    const float* Wv      = (const float*)d_in[2];
    const float* bv      = (const float*)d_in[3];
    const float* Wk      = (const float*)d_in[4];
    const float* bk      = (const float*)d_in[5];
    float* out = (float*)d_out;

    float* vw = (float*)d_ws;                       // 262144 floats
    float* kw = vw + (size_t)N_B * C_CH * L_T;      // 262144 floats

    proj_kernel<<<(N_B * C_CH * L_T) / 256, 256, 0, stream>>>(token, Wv, bv, Wk, bk, vw, kw);

    attn_kernel<<<N_B * HEADS * (HW_PX / 256), 256, 0, stream>>>(feature, vw, kw, out);
}